// Round 20
// baseline (153.771 us; speedup 1.0000x reference)
//
#include <hip/hip_runtime.h>
#include <math.h>

#define NTOK 16384      // 4 * 4096 tokens
#define DIM 2048
#define NEXP 64
#define TOPK 8
#define BT 64           // tokens per block (lane = token)
#define KC 32           // two numpy 16-blocks per stage
#define NCHUNK (DIM / KC)   // 64
#define PADK 36         // LDS row stride floats; b128 reads 2-way (free)
#define NBLK (NTOK / BT)    // 256 blocks, 1/CU, 16 waves/CU = 4/SIMD
#define EPW 4           // experts per wave (16 waves x 4 = 64)

typedef float f2 __attribute__((ext_vector_type(2)));
typedef float f4 __attribute__((ext_vector_type(4)));

// VOP3P packed f32: two independent IEEE f32 ops per instr, component-wise
// bit-identical to the scalar sequence they replace.
__device__ __forceinline__ f2 pk_mul(f2 a, f2 b) {
    f2 d; asm("v_pk_mul_f32 %0, %1, %2" : "=v"(d) : "v"(a), "v"(b)); return d;
}
__device__ __forceinline__ f2 pk_add(f2 a, f2 b) {
    f2 d; asm("v_pk_add_f32 %0, %1, %2" : "=v"(d) : "v"(a), "v"(b)); return d;
}

__global__ __launch_bounds__(1024, 1) void moe_gate_np(
    const float* __restrict__ h, const float* __restrict__ W,
    float* __restrict__ out, float* __restrict__ wsum)
{
#pragma clang fp contract(off)
    __shared__ float sA[2][BT * PADK];       // h tile  [64][36] dbuf (18.4 KB)
    __shared__ float sB[2][NEXP * PADK];     // W tile  [64][36] dbuf (18.4 KB)
    __shared__ float lg[BT][NEXP + 2];       // logits -> p values (16.9 KB)

    const int tid  = threadIdx.x;            // 0..1023
    const int lane = tid & 63;               // token within tile
    const int wv   = tid >> 6;               // 0..15: expert quartet
    const int blk  = blockIdx.x;
    const long tok0 = (long)blk * BT;
    const float* hA = h + tok0 * DIM;
    const int e0 = wv * EPW;

    // ---- staging map: waves 0-7 stage A, waves 8-15 stage B; 1 f4 each ----
    const int sidx = tid & 511;
    const int srow = sidx >> 3;              // 0..63
    const int scol = (sidx & 7) * 4;         // 0..28
    const bool isA = tid < 512;
    const float* gsrc = isA ? (hA + (long)srow * DIM + scol)
                            : (W  + (long)srow * DIM + scol);
    float* l0 = isA ? &sA[0][srow * PADK + scol] : &sB[0][srow * PADK + scol];
    float* l1 = isA ? &sA[1][srow * PADK + scol] : &sB[1][srow * PADK + scol];

    // prologue: stage 0 -> buf0, then prefetch stage 1 into regs
    f4 pa = *(const f4*)gsrc;
    *(f4*)l0 = pa;
    pa = *(const f4*)(gsrc + KC);

    // accumulators: 4 experts x chain pairs (c0,c1) and (c2,c3)
    f2 a01[EPW], a23[EPW];
    #pragma unroll
    for (int j = 0; j < EPW; ++j) { a01[j] = (f2)(0.f); a23[j] = (f2)(0.f); }

    for (int kc = 0; kc < NCHUNK; ++kc) {
        __syncthreads();                     // single barrier per stage
        const int cur = kc & 1;

        if (kc + 1 < NCHUNK)                 // write next stage (regs -> LDS)
            *(f4*)(cur ? l0 : l1) = pa;
        if (kc + 2 < NCHUNK)                 // prefetch stage kc+2 (vmcnt-counted)
            pa = *(const f4*)(gsrc + (long)(kc + 2) * KC);

        // 2 numpy 16-blocks per stage, strictly ascending k
        #pragma unroll
        for (int s = 0; s < 2; ++s) {
            // A: this lane's token, 16 k-values (4 x ds_read_b128, per-lane)
            f4 af[4];
            const float* ab = &sA[cur][lane * PADK + s * 16];
            #pragma unroll
            for (int v = 0; v < 4; ++v) af[v] = *(const f4*)(ab + 4 * v);

            f2 alo[4], ahi[4];               // .xy -> chains 0,1 ; .zw -> chains 2,3
            #pragma unroll
            for (int v = 0; v < 4; ++v) {
                alo[v] = __builtin_shufflevector(af[v], af[v], 0, 1);
                ahi[v] = __builtin_shufflevector(af[v], af[v], 2, 3);
            }

            // B: 4 experts, wave-uniform broadcast ds_read_b128 (in-order ->
            // counted lgkmcnt waits; offsets fold into instruction immediates)
            const float* bb = &sB[cur][e0 * PADK + s * 16];
            #pragma unroll
            for (int j = 0; j < EPW; ++j) {
                f4 Bf[4];
                #pragma unroll
                for (int v = 0; v < 4; ++v)
                    Bf[v] = *(const f4*)(bb + j * PADK + 4 * v);

                f2 blo[4], bhi[4];
                #pragma unroll
                for (int v = 0; v < 4; ++v) {
                    blo[v] = __builtin_shufflevector(Bf[v], Bf[v], 0, 1);
                    bhi[v] = __builtin_shufflevector(Bf[v], Bf[v], 2, 3);
                }
                f2 x;
                // chains 0,1: c = p0 + (p1 + (p2 + (p3 + c)))
                x = pk_add(pk_mul(blo[3], alo[3]), a01[j]);
                x = pk_add(pk_mul(blo[2], alo[2]), x);
                x = pk_add(pk_mul(blo[1], alo[1]), x);
                a01[j] = pk_add(pk_mul(blo[0], alo[0]), x);
                // chains 2,3
                x = pk_add(pk_mul(bhi[3], ahi[3]), a23[j]);
                x = pk_add(pk_mul(bhi[2], ahi[2]), x);
                x = pk_add(pk_mul(bhi[1], ahi[1]), x);
                a23[j] = pk_add(pk_mul(bhi[0], ahi[0]), x);
            }
        }
    }

    // horizontal combine: (c0+c2)+(c1+c3)  (npyv_sum_f32 SSE2 order)
    #pragma unroll
    for (int j = 0; j < EPW; ++j) {
        f2 s2 = pk_add(a01[j], a23[j]);       // (c0+c2, c1+c3)
        lg[lane][e0 + j] = s2.x + s2.y;
    }
    __syncthreads();

    // ---- per-token f32 softmax + stable top-8, numpy rounding orders ----
    float auxacc = 0.f;

    for (int tt = 0; tt < 4; ++tt) {
        const int t = wv * 4 + tt;            // 16 waves x 4 tokens
        const float s = lg[t][lane];          // lane = expert here

        float m = s;                          // max: exact, order-independent
        #pragma unroll
        for (int off = 32; off >= 1; off >>= 1)
            m = fmaxf(m, __shfl_xor(m, off));

        const float p = expf(s - m);
        lg[t][lane] = p;                      // own wave's rows only
        __asm__ volatile("" ::: "memory");    // compiler barrier; DS in-order per wave

        // np.sum pairwise, n=64: 8 stride-8 serial chains + fixed combine
        float r0s = lg[t][0], r1s = lg[t][1], r2s = lg[t][2], r3s = lg[t][3];
        float r4s = lg[t][4], r5s = lg[t][5], r6s = lg[t][6], r7s = lg[t][7];
        #pragma unroll
        for (int i = 1; i < 8; ++i) {
            r0s += lg[t][8 * i + 0]; r1s += lg[t][8 * i + 1];
            r2s += lg[t][8 * i + 2]; r3s += lg[t][8 * i + 3];
            r4s += lg[t][8 * i + 4]; r5s += lg[t][8 * i + 5];
            r6s += lg[t][8 * i + 6]; r7s += lg[t][8 * i + 7];
        }
        const float S = ((r0s + r1s) + (r2s + r3s)) + ((r4s + r5s) + (r6s + r7s));

        const float score = p / S;            // IEEE f32 divide, matches np
        auxacc += score;

        // stable top-8: max with lowest-index tie-break (stable argsort)
        float cv = score;
        float myv = 0.f;
        int   myi = 0;
        #pragma unroll
        for (int i = 0; i < TOPK; ++i) {
            float v = cv;
            int idx = lane;
            #pragma unroll
            for (int off = 32; off >= 1; off >>= 1) {
                float v2 = __shfl_xor(v, off);
                int   i2 = __shfl_xor(idx, off);
                if (v2 > v || (v2 == v && i2 < idx)) { v = v2; idx = i2; }
            }
            if (lane == i)   { myv = v; myi = idx; }
            if (lane == idx) cv = -1.f;       // scores >= 0
        }

        // weight denom: np.sum n=8 -> serial ascending
        float S8 = 0.f;
        #pragma unroll
        for (int r = 0; r < TOPK; ++r) S8 += __shfl(myv, r);

        if (lane < TOPK) {
            const long o = (tok0 + t) * TOPK + lane;
            out[o]                     = (float)myi;   // expert_ids
            out[(long)NTOK * TOPK + o] = myv / S8;     // expert_weight
        }
    }

    const int b = blk >> 6;                  // 64 blocks per batch row
    atomicAdd(&wsum[b * NEXP + lane], auxacc);
}

__global__ void aux_finish(const float* __restrict__ wsum, float* __restrict__ out)
{
    const int lane = threadIdx.x;            // 64 threads
    float a = 0.f;
    #pragma unroll
    for (int b = 0; b < 4; ++b) {
        const float v = wsum[b * NEXP + lane] * (1.0f / 4096.0f);
        a = fmaf(v, v, a);
    }
    #pragma unroll
    for (int off = 32; off >= 1; off >>= 1)
        a += __shfl_xor(a, off);
    if (lane == 0)
        out[2L * NTOK * TOPK] = a * 0.25f * (float)NEXP * 0.01f;
}

extern "C" void kernel_launch(void* const* d_in, const int* in_sizes, int n_in,
                              void* d_out, int out_size, void* d_ws, size_t ws_size,
                              hipStream_t stream) {
    const float* h = (const float*)d_in[0];
    const float* W = (const float*)d_in[1];
    float* out  = (float*)d_out;
    float* wsum = (float*)d_ws;              // 256 f32

    hipMemsetAsync(d_ws, 0, 1024, stream);
    moe_gate_np<<<NBLK, 1024, 0, stream>>>(h, W, out, wsum);
    aux_finish<<<1, 64, 0, stream>>>(wsum, out);
}

// Round 21
// 147.442 us; speedup vs baseline: 1.0429x; 1.0429x over previous
//
#include <hip/hip_runtime.h>
#include <math.h>

#define NTOK 16384      // 4 * 4096 tokens
#define DIM 2048
#define NEXP 64
#define TOPK 8
#define BT 64           // tokens per block (lane = token)
#define KC 32           // two numpy 16-blocks per stage
#define NCHUNK (DIM / KC)   // 64
#define PADK 36         // LDS row stride floats; b128 reads 2-way (free)
#define NBLK (NTOK / BT)    // 256 blocks, 1/CU, 16 waves/CU = 4/SIMD
#define EPW 4           // experts per wave (16 waves x 4 = 64)

typedef float f2  __attribute__((ext_vector_type(2)));
typedef float f4  __attribute__((ext_vector_type(4)));
typedef float f16 __attribute__((ext_vector_type(16)));

// VOP3P packed f32: two independent IEEE f32 ops per instr, component-wise
// bit-identical to the scalar sequence they replace.
__device__ __forceinline__ f2 pk_mul_sv(f2 bs, f2 av) {   // B from SGPR pair
    f2 d; asm("v_pk_mul_f32 %0, %1, %2" : "=v"(d) : "s"(bs), "v"(av)); return d;
}
__device__ __forceinline__ f2 pk_mul(f2 a, f2 b) {
    f2 d; asm("v_pk_mul_f32 %0, %1, %2" : "=v"(d) : "v"(a), "v"(b)); return d;
}
__device__ __forceinline__ f2 pk_add(f2 a, f2 b) {
    f2 d; asm("v_pk_add_f32 %0, %1, %2" : "=v"(d) : "v"(a), "v"(b)); return d;
}

__global__ __launch_bounds__(1024, 1) void moe_gate_np(
    const float* __restrict__ h, const float* __restrict__ W,
    float* __restrict__ out, float* __restrict__ wsum)
{
#pragma clang fp contract(off)
    __shared__ float sA[2][BT * PADK];       // h tile  [64][36] dbuf (18.4 KB)
    __shared__ float sBh[2][32 * PADK];      // W half-tile [32][36] dbuf (9.2 KB)
    __shared__ float lg[BT][NEXP + 2];       // logits -> p values (16.9 KB)

    const int tid  = threadIdx.x;            // 0..1023
    const int lane = tid & 63;               // token within tile
    const int wv   = tid >> 6;               // 0..15: expert quartet
    const int blk  = blockIdx.x;
    const long tok0 = (long)blk * BT;
    const float* hA = h + tok0 * DIM;
    const int e0 = wv * EPW;

    // wave-uniform expert base for the SMEM half (experts e0, e0+1)
    const int e0s = __builtin_amdgcn_readfirstlane(wv) * EPW;
    const float* wb = W + (long)e0s * DIM;

    // ---- staging map: waves 0-7 stage A; waves 8-11 stage B-half; 12-15 idle ----
    // B-half = experts with (e & 3) >= 2: local row br (0..31) <-> expert
    // (br>>1)*4 + 2 + (br&1). One f4 per stager per stage.
    const bool isA  = tid < 512;
    const bool doSt = tid < 768;
    const int  aRow = (tid & 511) >> 3;          // 0..63
    const int  aCol = (tid & 7) * 4;             // 0..28
    const int  bRow = (tid - 512) >> 3;          // 0..31 (B stagers)
    const int  bExp = (bRow >> 1) * 4 + 2 + (bRow & 1);

    const float* gsrc = isA ? (hA + (long)aRow * DIM + aCol)
                            : (W  + (long)bExp * DIM + aCol);
    float* l0 = isA ? &sA[0][aRow * PADK + aCol] : &sBh[0][bRow * PADK + aCol];
    float* l1 = isA ? &sA[1][aRow * PADK + aCol] : &sBh[1][bRow * PADK + aCol];

    // prologue: stage 0 -> buf0, then prefetch stage 1 into regs
    f4 pa;
    if (doSt) {
        pa = *(const f4*)gsrc;
        *(f4*)l0 = pa;
        pa = *(const f4*)(gsrc + KC);
    }

    // accumulators: 4 experts x chain pairs (c0,c1) and (c2,c3)
    f2 a01[EPW], a23[EPW];
    #pragma unroll
    for (int j = 0; j < EPW; ++j) { a01[j] = (f2)(0.f); a23[j] = (f2)(0.f); }

    for (int kc = 0; kc < NCHUNK; ++kc) {
        __syncthreads();                     // single barrier per stage
        const int cur = kc & 1;

        if (doSt && kc + 1 < NCHUNK)         // write next stage (regs -> LDS)
            *(f4*)(cur ? l0 : l1) = pa;
        if (doSt && kc + 2 < NCHUNK)         // prefetch stage kc+2 (vmcnt-counted)
            pa = *(const f4*)(gsrc + (long)(kc + 2) * KC);

        // 2 numpy 16-blocks per stage, strictly ascending k
        #pragma unroll
        for (int s = 0; s < 2; ++s) {
            const int kb = kc * KC + s * 16;

            // SMEM half: experts e0, e0+1 (one s_load_dwordx16 each)
            f16 Bs[2];
            Bs[0] = *(const f16*)(wb + kb);
            Bs[1] = *(const f16*)(wb + DIM + kb);

            // LDS half: experts e0+2, e0+3 (broadcast ds_read_b128)
            const float* bb = &sBh[cur][(2 * wv) * PADK + s * 16];
            f4 Bl[2][4];
            #pragma unroll
            for (int v = 0; v < 4; ++v) {
                Bl[0][v] = *(const f4*)(bb + 4 * v);
                Bl[1][v] = *(const f4*)(bb + PADK + 4 * v);
            }

            // A: this lane's token, 16 k-values (4 x ds_read_b128)
            f4 af[4];
            const float* ab = &sA[cur][lane * PADK + s * 16];
            #pragma unroll
            for (int v = 0; v < 4; ++v) af[v] = *(const f4*)(ab + 4 * v);

            f2 alo[4], ahi[4];               // .xy -> chains 0,1 ; .zw -> chains 2,3
            #pragma unroll
            for (int v = 0; v < 4; ++v) {
                alo[v] = __builtin_shufflevector(af[v], af[v], 0, 1);
                ahi[v] = __builtin_shufflevector(af[v], af[v], 2, 3);
            }

            // experts 0,1: B pairs from SGPRs (constant-index extracts)
            #pragma unroll
            for (int j = 0; j < 2; ++j) {
                f2 blo[4], bhi[4];
                blo[0] = __builtin_shufflevector(Bs[j], Bs[j],  0,  1);
                bhi[0] = __builtin_shufflevector(Bs[j], Bs[j],  2,  3);
                blo[1] = __builtin_shufflevector(Bs[j], Bs[j],  4,  5);
                bhi[1] = __builtin_shufflevector(Bs[j], Bs[j],  6,  7);
                blo[2] = __builtin_shufflevector(Bs[j], Bs[j],  8,  9);
                bhi[2] = __builtin_shufflevector(Bs[j], Bs[j], 10, 11);
                blo[3] = __builtin_shufflevector(Bs[j], Bs[j], 12, 13);
                bhi[3] = __builtin_shufflevector(Bs[j], Bs[j], 14, 15);
                f2 x;
                // chains 0,1: c = p0 + (p1 + (p2 + (p3 + c)))
                x = pk_add(pk_mul_sv(blo[3], alo[3]), a01[j]);
                x = pk_add(pk_mul_sv(blo[2], alo[2]), x);
                x = pk_add(pk_mul_sv(blo[1], alo[1]), x);
                a01[j] = pk_add(pk_mul_sv(blo[0], alo[0]), x);
                // chains 2,3
                x = pk_add(pk_mul_sv(bhi[3], ahi[3]), a23[j]);
                x = pk_add(pk_mul_sv(bhi[2], ahi[2]), x);
                x = pk_add(pk_mul_sv(bhi[1], ahi[1]), x);
                a23[j] = pk_add(pk_mul_sv(bhi[0], ahi[0]), x);
            }

            // experts 2,3: B pairs from LDS broadcast (VGPRs)
            #pragma unroll
            for (int j = 0; j < 2; ++j) {
                f2 blo[4], bhi[4];
                #pragma unroll
                for (int v = 0; v < 4; ++v) {
                    blo[v] = __builtin_shufflevector(Bl[j][v], Bl[j][v], 0, 1);
                    bhi[v] = __builtin_shufflevector(Bl[j][v], Bl[j][v], 2, 3);
                }
                f2 x;
                x = pk_add(pk_mul(blo[3], alo[3]), a01[2 + j]);
                x = pk_add(pk_mul(blo[2], alo[2]), x);
                x = pk_add(pk_mul(blo[1], alo[1]), x);
                a01[2 + j] = pk_add(pk_mul(blo[0], alo[0]), x);
                x = pk_add(pk_mul(bhi[3], ahi[3]), a23[2 + j]);
                x = pk_add(pk_mul(bhi[2], ahi[2]), x);
                x = pk_add(pk_mul(bhi[1], ahi[1]), x);
                a23[2 + j] = pk_add(pk_mul(bhi[0], ahi[0]), x);
            }
        }
    }

    // horizontal combine: (c0+c2)+(c1+c3)  (npyv_sum_f32 SSE2 order)
    #pragma unroll
    for (int j = 0; j < EPW; ++j) {
        f2 s2 = pk_add(a01[j], a23[j]);       // (c0+c2, c1+c3)
        lg[lane][e0 + j] = s2.x + s2.y;
    }
    __syncthreads();

    // ---- per-token f32 softmax + stable top-8, numpy rounding orders ----
    float auxacc = 0.f;

    for (int tt = 0; tt < 4; ++tt) {
        const int t = wv * 4 + tt;            // 16 waves x 4 tokens
        const float s = lg[t][lane];          // lane = expert here

        float m = s;                          // max: exact, order-independent
        #pragma unroll
        for (int off = 32; off >= 1; off >>= 1)
            m = fmaxf(m, __shfl_xor(m, off));

        const float p = expf(s - m);
        lg[t][lane] = p;                      // own wave's rows only
        __asm__ volatile("" ::: "memory");    // compiler barrier; DS in-order per wave

        // np.sum pairwise, n=64: 8 stride-8 serial chains + fixed combine
        float r0s = lg[t][0], r1s = lg[t][1], r2s = lg[t][2], r3s = lg[t][3];
        float r4s = lg[t][4], r5s = lg[t][5], r6s = lg[t][6], r7s = lg[t][7];
        #pragma unroll
        for (int i = 1; i < 8; ++i) {
            r0s += lg[t][8 * i + 0]; r1s += lg[t][8 * i + 1];
            r2s += lg[t][8 * i + 2]; r3s += lg[t][8 * i + 3];
            r4s += lg[t][8 * i + 4]; r5s += lg[t][8 * i + 5];
            r6s += lg[t][8 * i + 6]; r7s += lg[t][8 * i + 7];
        }
        const float S = ((r0s + r1s) + (r2s + r3s)) + ((r4s + r5s) + (r6s + r7s));

        const float score = p / S;            // IEEE f32 divide, matches np
        auxacc += score;

        // stable top-8: max with lowest-index tie-break (stable argsort)
        float cv = score;
        float myv = 0.f;
        int   myi = 0;
        #pragma unroll
        for (int i = 0; i < TOPK; ++i) {
            float v = cv;
            int idx = lane;
            #pragma unroll
            for (int off = 32; off >= 1; off >>= 1) {
                float v2 = __shfl_xor(v, off);
                int   i2 = __shfl_xor(idx, off);
                if (v2 > v || (v2 == v && i2 < idx)) { v = v2; idx = i2; }
            }
            if (lane == i)   { myv = v; myi = idx; }
            if (lane == idx) cv = -1.f;       // scores >= 0
        }

        // weight denom: np.sum n=8 -> serial ascending
        float S8 = 0.f;
        #pragma unroll
        for (int r = 0; r < TOPK; ++r) S8 += __shfl(myv, r);

        if (lane < TOPK) {
            const long o = (tok0 + t) * TOPK + lane;
            out[o]                     = (float)myi;   // expert_ids
            out[(long)NTOK * TOPK + o] = myv / S8;     // expert_weight
        }
    }

    const int b = blk >> 6;                  // 64 blocks per batch row
    atomicAdd(&wsum[b * NEXP + lane], auxacc);
}

__global__ void aux_finish(const float* __restrict__ wsum, float* __restrict__ out)
{
    const int lane = threadIdx.x;            // 64 threads
    float a = 0.f;
    #pragma unroll
    for (int b = 0; b < 4; ++b) {
        const float v = wsum[b * NEXP + lane] * (1.0f / 4096.0f);
        a = fmaf(v, v, a);
    }
    #pragma unroll
    for (int off = 32; off >= 1; off >>= 1)
        a += __shfl_xor(a, off);
    if (lane == 0)
        out[2L * NTOK * TOPK] = a * 0.25f * (float)NEXP * 0.01f;
}

extern "C" void kernel_launch(void* const* d_in, const int* in_sizes, int n_in,
                              void* d_out, int out_size, void* d_ws, size_t ws_size,
                              hipStream_t stream) {
    const float* h = (const float*)d_in[0];
    const float* W = (const float*)d_in[1];
    float* out  = (float*)d_out;
    float* wsum = (float*)d_ws;              // 256 f32

    hipMemsetAsync(d_ws, 0, 1024, stream);
    moe_gate_np<<<NBLK, 1024, 0, stream>>>(h, W, out, wsum);
    aux_finish<<<1, 64, 0, stream>>>(wsum, out);
}

// Round 22
// 142.795 us; speedup vs baseline: 1.0769x; 1.0325x over previous
//
#include <hip/hip_runtime.h>
#include <math.h>

#define NTOK 16384      // 4 * 4096 tokens
#define DIM 2048
#define NEXP 64
#define TOPK 8
#define BT 64           // tokens per block (lane = token)
#define KC 64           // four numpy 16-blocks per stage
#define NCHUNK (DIM / KC)   // 32
#define PADK 68         // LDS row stride floats
#define NBLK (NTOK / BT)    // 256 blocks, 1/CU, 16 waves/CU = 4/SIMD
#define EPW 4           // experts per wave (16 waves x 4 = 64)

typedef float f2 __attribute__((ext_vector_type(2)));
typedef float f4 __attribute__((ext_vector_type(4)));

// VOP3P packed f32: two independent IEEE f32 ops per instr, component-wise
// bit-identical to the scalar sequence. B comes in as an SGPR pair (src0).
__device__ __forceinline__ f2 pk_mul_sv(f2 bs, f2 av) {
    f2 d; asm("v_pk_mul_f32 %0, %1, %2" : "=v"(d) : "s"(bs), "v"(av)); return d;
}
__device__ __forceinline__ f2 pk_add(f2 a, f2 b) {
    f2 d; asm("v_pk_add_f32 %0, %1, %2" : "=v"(d) : "v"(a), "v"(b)); return d;
}

__global__ __launch_bounds__(1024, 1) void moe_gate_np(
    const float* __restrict__ h, const float* __restrict__ W,
    float* __restrict__ out, float* __restrict__ wsum)
{
#pragma clang fp contract(off)
    __shared__ float sA[2][BT * PADK];       // double-buffered h tile (34.8 KB)
    __shared__ float lg[BT][NEXP + 2];       // logits -> p values (16.9 KB)

    const int tid  = threadIdx.x;            // 0..1023
    const int lane = tid & 63;               // token within tile
    const int wv   = tid >> 6;               // 0..15: expert quartet
    const int blk  = blockIdx.x;
    const long tok0 = (long)blk * BT;
    const float* hA = h + tok0 * DIM;

    // wave-uniform expert base -> scalar (s_load) W accesses
    const int e0 = __builtin_amdgcn_readfirstlane(wv) * EPW;
    const float* wb = W + (long)e0 * DIM;

    // ---- A staging map: 1 f4 per thread per stage (64 rows x 64 cols) ----
    const int rs = tid >> 4;                 // 0..63
    const int cs = (tid & 15) * 4;           // 0..60

    // prologue: stage 0 -> buf0 (no barrier needed; loop-top barrier orders it),
    // then prefetch stage 1 into regs
    f4 pa = *(const f4*)(hA + (long)rs * DIM + cs);
    *(f4*)&sA[0][rs * PADK + cs] = pa;
    pa = *(const f4*)(hA + (long)rs * DIM + KC + cs);

    // accumulators: 4 experts x chain pairs (c0,c1) and (c2,c3)
    f2 a01[EPW], a23[EPW];
    #pragma unroll
    for (int j = 0; j < EPW; ++j) { a01[j] = (f2)(0.f); a23[j] = (f2)(0.f); }

    for (int kc = 0; kc < NCHUNK; ++kc) {
        __syncthreads();                     // single barrier per stage:
        const int cur = kc & 1;              // orders prev reads of buf[cur^1]
                                             // before this stage's writes
        if (kc + 1 < NCHUNK)                 // write next stage (regs -> LDS)
            *(f4*)&sA[cur ^ 1][rs * PADK + cs] = pa;
        if (kc + 2 < NCHUNK)                 // prefetch stage kc+2 (vmcnt-counted)
            pa = *(const f4*)(hA + (long)rs * DIM + (long)(kc + 2) * KC + cs);

        // 4 numpy 16-blocks per stage, strictly ascending k
        #pragma unroll
        for (int s = 0; s < 4; ++s) {
            const int kb = kc * KC + s * 16;

            // B batch: 4 experts x 4 f4, wave-uniform -> s_load (64 SGPR)
            f4 B[EPW][4];
            #pragma unroll
            for (int j = 0; j < EPW; ++j)
                #pragma unroll
                for (int q = 0; q < 4; ++q)
                    B[j][q] = *(const f4*)(wb + (long)j * DIM + kb + 4 * q);

            // A: this lane's token, 16 k-values (4 x ds_read_b128)
            f4 af[4];
            const float* ab = &sA[cur][lane * PADK + s * 16];
            #pragma unroll
            for (int v = 0; v < 4; ++v) af[v] = *(const f4*)(ab + 4 * v);

            f2 alo[4], ahi[4];               // .xy -> chains 0,1 ; .zw -> chains 2,3
            #pragma unroll
            for (int v = 0; v < 4; ++v) {
                alo[v] = __builtin_shufflevector(af[v], af[v], 0, 1);
                ahi[v] = __builtin_shufflevector(af[v], af[v], 2, 3);
            }

            #pragma unroll
            for (int j = 0; j < EPW; ++j) {
                f2 blo[4], bhi[4];           // uniform values -> SGPR pairs
                #pragma unroll
                for (int v = 0; v < 4; ++v) {
                    blo[v] = __builtin_shufflevector(B[j][v], B[j][v], 0, 1);
                    bhi[v] = __builtin_shufflevector(B[j][v], B[j][v], 2, 3);
                }
                f2 x;
                // chains 0,1: c = p0 + (p1 + (p2 + (p3 + c)))
                x = pk_add(pk_mul_sv(blo[3], alo[3]), a01[j]);
                x = pk_add(pk_mul_sv(blo[2], alo[2]), x);
                x = pk_add(pk_mul_sv(blo[1], alo[1]), x);
                a01[j] = pk_add(pk_mul_sv(blo[0], alo[0]), x);
                // chains 2,3
                x = pk_add(pk_mul_sv(bhi[3], ahi[3]), a23[j]);
                x = pk_add(pk_mul_sv(bhi[2], ahi[2]), x);
                x = pk_add(pk_mul_sv(bhi[1], ahi[1]), x);
                a23[j] = pk_add(pk_mul_sv(bhi[0], ahi[0]), x);
            }
        }
    }

    // horizontal combine: (c0+c2)+(c1+c3)  (npyv_sum_f32 SSE2 order)
    #pragma unroll
    for (int j = 0; j < EPW; ++j) {
        f2 s2 = pk_add(a01[j], a23[j]);       // (c0+c2, c1+c3)
        lg[lane][e0 + j] = s2.x + s2.y;
    }
    __syncthreads();

    // ---- per-token f32 softmax + stable top-8, numpy rounding orders ----
    float auxacc = 0.f;

    for (int tt = 0; tt < 4; ++tt) {
        const int t = wv * 4 + tt;            // 16 waves x 4 tokens
        const float s = lg[t][lane];          // lane = expert here

        float m = s;                          // max: exact, order-independent
        #pragma unroll
        for (int off = 32; off >= 1; off >>= 1)
            m = fmaxf(m, __shfl_xor(m, off));

        const float p = expf(s - m);
        lg[t][lane] = p;                      // own wave's rows only
        __asm__ volatile("" ::: "memory");    // compiler barrier; DS in-order per wave

        // np.sum pairwise, n=64: 8 stride-8 serial chains + fixed combine
        float r0s = lg[t][0], r1s = lg[t][1], r2s = lg[t][2], r3s = lg[t][3];
        float r4s = lg[t][4], r5s = lg[t][5], r6s = lg[t][6], r7s = lg[t][7];
        #pragma unroll
        for (int i = 1; i < 8; ++i) {
            r0s += lg[t][8 * i + 0]; r1s += lg[t][8 * i + 1];
            r2s += lg[t][8 * i + 2]; r3s += lg[t][8 * i + 3];
            r4s += lg[t][8 * i + 4]; r5s += lg[t][8 * i + 5];
            r6s += lg[t][8 * i + 6]; r7s += lg[t][8 * i + 7];
        }
        const float S = ((r0s + r1s) + (r2s + r3s)) + ((r4s + r5s) + (r6s + r7s));

        const float score = p / S;            // IEEE f32 divide, matches np
        auxacc += score;

        // stable top-8: max with lowest-index tie-break (stable argsort)
        float cv = score;
        float myv = 0.f;
        int   myi = 0;
        #pragma unroll
        for (int i = 0; i < TOPK; ++i) {
            float v = cv;
            int idx = lane;
            #pragma unroll
            for (int off = 32; off >= 1; off >>= 1) {
                float v2 = __shfl_xor(v, off);
                int   i2 = __shfl_xor(idx, off);
                if (v2 > v || (v2 == v && i2 < idx)) { v = v2; idx = i2; }
            }
            if (lane == i)   { myv = v; myi = idx; }
            if (lane == idx) cv = -1.f;       // scores >= 0
        }

        // weight denom: np.sum n=8 -> serial ascending
        float S8 = 0.f;
        #pragma unroll
        for (int r = 0; r < TOPK; ++r) S8 += __shfl(myv, r);

        if (lane < TOPK) {
            const long o = (tok0 + t) * TOPK + lane;
            out[o]                     = (float)myi;   // expert_ids
            out[(long)NTOK * TOPK + o] = myv / S8;     // expert_weight
        }
    }

    const int b = blk >> 6;                  // 64 blocks per batch row
    atomicAdd(&wsum[b * NEXP + lane], auxacc);
}

__global__ void aux_finish(const float* __restrict__ wsum, float* __restrict__ out)
{
    const int lane = threadIdx.x;            // 64 threads
    float a = 0.f;
    #pragma unroll
    for (int b = 0; b < 4; ++b) {
        const float v = wsum[b * NEXP + lane] * (1.0f / 4096.0f);
        a = fmaf(v, v, a);
    }
    #pragma unroll
    for (int off = 32; off >= 1; off >>= 1)
        a += __shfl_xor(a, off);
    if (lane == 0)
        out[2L * NTOK * TOPK] = a * 0.25f * (float)NEXP * 0.01f;
}

extern "C" void kernel_launch(void* const* d_in, const int* in_sizes, int n_in,
                              void* d_out, int out_size, void* d_ws, size_t ws_size,
                              hipStream_t stream) {
    const float* h = (const float*)d_in[0];
    const float* W = (const float*)d_in[1];
    float* out  = (float*)d_out;
    float* wsum = (float*)d_ws;              // 256 f32

    hipMemsetAsync(d_ws, 0, 1024, stream);
    moe_gate_np<<<NBLK, 1024, 0, stream>>>(h, W, out, wsum);
    aux_finish<<<1, 64, 0, stream>>>(wsum, out);
}